// Round 10
// baseline (148.092 us; speedup 1.0000x reference)
//
#include <hip/hip_runtime.h>

// Truncated signature, depth=3, C=8, B=512, L=8192.
// Kernel 1: one wave per (sample, chunk); sequential Chen steps over the chunk.
//   lane (a,b)=(lane>>3, lane&7) owns S2[a][b], S3[a][b][0..7].
//   Direct form: S3[k] += cf * dx2[k][u], cf = S2 + S1*db/2 + da*db/6.
//   Broadcast operand dx2[k][u] is pulled from the STAGING REGISTERS via
//   v_readlane (lane k*8+quad) -> SGPR operand; S3 accumulated as 4 k-pairs
//   with packed fp32 fma (v_pk_fma_f32, double-rate on CDNA4).
//   LDS holds dx/2 in [c][t] (stride 68) only for per-lane da/db octet reads.
//   Per-wave private LDS slice, no barriers. Compute split into an e0t half
//   and an e1t half (no select, smaller live set; launch_bounds(256,4) to
//   avoid R9's spill regression).
// Kernel 2: per-sample in-order Chen combine of the G chunk signatures.

typedef float f2 __attribute__((ext_vector_type(2)));

constexpr int B_ = 512;
constexpr int C_ = 8;
constexpr int L_ = 8192;
constexpr int NINC = L_ - 1;      // 8191 increments
constexpr int SIGDIM = 584;       // 8 + 64 + 512
constexpr int TILE = 64;          // steps per LDS tile
constexpr int BSTR = 68;          // dx row stride (floats): 68%32=4 spreads rows
constexpr int BWSZ = C_ * BSTR;   // 544 floats per wave

static __device__ __forceinline__ float rl(float v, int l) {
  return __int_as_float(__builtin_amdgcn_readlane(__float_as_int(v), l));
}

// Recurrence on halved increments (DA=da/2, DB=db/2), true-scale cf/S2/S1.
#define RSTEP(DA, DB, CFV)                                    \
  do {                                                        \
    const float w_ = __builtin_fmaf((DA), (2.f/3.f), s1a);    \
    const float z_ = __builtin_fmaf((DA), (4.f/3.f), s1a);    \
    (CFV) = __builtin_fmaf((DB), w_, S2);                     \
    S2  = __builtin_fmaf((DB), z_, (CFV));                    \
    s1a = __builtin_fmaf((DA), 2.f, s1a);                     \
  } while (0)

// One step's S3 update: broadcast component EC from lanes k*8+Q, packed over
// k-pairs (0,1),(2,3),(4,5),(6,7).
#define S3ROW(EC, Q, CF)                                                     \
  do {                                                                       \
    const f2 cf2_ = {(CF), (CF)};                                            \
    S3p[0] = __builtin_elementwise_fma(                                      \
        cf2_, f2{rl((EC), 0 + (Q)), rl((EC), 8 + (Q))}, S3p[0]);             \
    S3p[1] = __builtin_elementwise_fma(                                      \
        cf2_, f2{rl((EC), 16 + (Q)), rl((EC), 24 + (Q))}, S3p[1]);           \
    S3p[2] = __builtin_elementwise_fma(                                      \
        cf2_, f2{rl((EC), 32 + (Q)), rl((EC), 40 + (Q))}, S3p[2]);           \
    S3p[3] = __builtin_elementwise_fma(                                      \
        cf2_, f2{rl((EC), 48 + (Q)), rl((EC), 56 + (Q))}, S3p[3]);           \
  } while (0)

// Half-block: 4 steps; E = one staging diff float4 (quad Q), AV/BV = da/db.
#define HB(E, Q, AV, BV)                                      \
  do {                                                        \
    float cf_;                                                \
    RSTEP((AV).x, (BV).x, cf_); S3ROW((E).x, (Q), cf_);       \
    RSTEP((AV).y, (BV).y, cf_); S3ROW((E).y, (Q), cf_);       \
    RSTEP((AV).z, (BV).z, cf_); S3ROW((E).z, (Q), cf_);       \
    RSTEP((AV).w, (BV).w, cf_); S3ROW((E).w, (Q), cf_);       \
  } while (0)

__global__ __launch_bounds__(256, 4)
void sig_chunks_kernel(const float* __restrict__ path, float* __restrict__ csig,
                       int G, int CPC) {
  __shared__ __align__(16) float Bs[4][BWSZ];   // 8.7 KB
  const int wid  = __builtin_amdgcn_readfirstlane((int)(threadIdx.x >> 6));
  const int lane = (int)(threadIdx.x & 63);
  const int ia = lane >> 3;   // 'a' == staging channel
  const int ib = lane & 7;    // 'b' == staging position
  const int wglob = __builtin_amdgcn_readfirstlane((int)blockIdx.x) * 4 + wid;
  const int samp = wglob / G;
  const int g    = wglob - samp * G;
  const int ts = g * CPC;
  const int te = (ts + CPC < NINC) ? (ts + CPC) : NINC;   // exclusive end
  const float* pbase = path + (size_t)samp * (C_ * L_);
  float* bs = Bs[wid];

  const int si = ib;
  const float* prow = pbase + ia * L_;     // per-lane staging row
  const int grp = lane & ~7;
  const float* pa = bs + ia * BSTR;
  const float* pb = bs + ib * BSTR;

  f2 S3p[4];
#pragma unroll
  for (int k = 0; k < 4; ++k) S3p[k] = f2{0.f, 0.f};
  float S2 = 0.f, s1a = 0.f;

  const int ntiles = (CPC + TILE - 1) / TILE;   // uniform across grid

  // prologue: prefetch tile 0 + boundary into regs
  float4 r0 = *(const float4*)(prow + ts + si * 4);
  float4 r1 = *(const float4*)(prow + ts + 32 + si * 4);
  float bnd = prow[ts + TILE];
  float4 e0t, e1t;   // current tile's halved diffs (this lane's 8 slots)

  for (int tt = 0; tt < ntiles; ++tt) {
    const int t0 = ts + tt * TILE;
    const int cnt_ = te - t0;
    const int cnt = (cnt_ < TILE) ? cnt_ : TILE;

    // ---- stage tile tt: halved diffs -> regs (kept!) + [c][t] LDS ----
    {
      const float4 v0 = r0, v1 = r1;
      const float sA = __shfl(v0.x, lane + 1);
      const float sB = __shfl(v1.x, grp);
      const float sC = __shfl(v1.x, lane + 1);
      const float n0 = (si == 7) ? sB : sA;
      const float n1 = (si == 7) ? bnd : sC;
      e0t.x = (v0.y - v0.x) * 0.5f;
      e0t.y = (v0.z - v0.y) * 0.5f;
      e0t.z = (v0.w - v0.z) * 0.5f;
      e0t.w = (n0 - v0.w) * 0.5f;
      e1t.x = (v1.y - v1.x) * 0.5f;
      e1t.y = (v1.z - v1.y) * 0.5f;
      e1t.z = (v1.w - v1.z) * 0.5f;
      e1t.w = (n1 - v1.w) * 0.5f;
      *(float4*)(bs + ia * BSTR + si * 4) = e0t;
      *(float4*)(bs + ia * BSTR + 32 + si * 4) = e1t;
    }

    // ---- prefetch tile tt+1 into regs ----
    if (tt + 1 < ntiles) {
      const int t1g = t0 + TILE;
      r0 = *(const float4*)(prow + t1g + si * 4);
      r1 = *(const float4*)(prow + t1g + 32 + si * 4);
      const int bn = t1g + TILE;
      bnd = (bn < L_) ? prow[bn] : 0.f;
    }

    if (cnt == TILE) {
      // first half: steps 0..31, broadcast from e0t
#pragma unroll
      for (int blk = 0; blk < 4; ++blk) {
        const int u0 = blk * 8;
        const float4 a0 = *(const float4*)(pa + u0);
        const float4 a1 = *(const float4*)(pa + u0 + 4);
        const float4 b0 = *(const float4*)(pb + u0);
        const float4 b1 = *(const float4*)(pb + u0 + 4);
        HB(e0t, blk * 2, a0, b0);
        HB(e0t, blk * 2 + 1, a1, b1);
      }
      // second half: steps 32..63, broadcast from e1t
#pragma unroll
      for (int blk = 0; blk < 4; ++blk) {
        const int u0 = 32 + blk * 8;
        const float4 a0 = *(const float4*)(pa + u0);
        const float4 a1 = *(const float4*)(pa + u0 + 4);
        const float4 b0 = *(const float4*)(pb + u0);
        const float4 b1 = *(const float4*)(pb + u0 + 4);
        HB(e1t, blk * 2, a0, b0);
        HB(e1t, blk * 2 + 1, a1, b1);
      }
    } else {
      // tail tile (last chunk only, cnt=63): uniform LDS b32 broadcast.
      for (int u = 0; u < cnt; ++u) {
        const float dav = pa[u];
        const float dbv = pb[u];
        float cf;
        RSTEP(dav, dbv, cf);
#pragma unroll
        for (int k = 0; k < 4; ++k) {
          S3p[k].x = __builtin_fmaf(cf, bs[(2 * k) * BSTR + u], S3p[k].x);
          S3p[k].y = __builtin_fmaf(cf, bs[(2 * k + 1) * BSTR + u], S3p[k].y);
        }
      }
    }
  }

  float* cs = csig + ((size_t)samp * G + g) * SIGDIM;
  if (ib == 0) cs[ia] = s1a;
  cs[8 + lane] = S2;
  float4 o0, o1;
  o0.x = 2.f * S3p[0].x; o0.y = 2.f * S3p[0].y;
  o0.z = 2.f * S3p[1].x; o0.w = 2.f * S3p[1].y;
  o1.x = 2.f * S3p[2].x; o1.y = 2.f * S3p[2].y;
  o1.z = 2.f * S3p[3].x; o1.w = 2.f * S3p[3].y;
  *(float4*)(cs + 72 + lane * 8)     = o0;
  *(float4*)(cs + 72 + lane * 8 + 4) = o1;
}

__global__ __launch_bounds__(256)
void sig_combine_kernel(const float* __restrict__ csig, float* __restrict__ out, int G) {
  const int wid  = __builtin_amdgcn_readfirstlane((int)(threadIdx.x >> 6));
  const int lane = (int)(threadIdx.x & 63);
  const int ia = lane >> 3, ib = lane & 7;
  const int samp = __builtin_amdgcn_readfirstlane((int)blockIdx.x) * 4 + wid;
  const float* base = csig + (size_t)samp * G * SIGDIM;

  float R1a = base[ia];
  float R2  = base[8 + lane];
  float R3[8];
#pragma unroll
  for (int k = 0; k < 8; ++k) R3[k] = base[72 + lane * 8 + k];

  for (int g = 1; g < G; ++g) {
    const float* T = base + g * SIGDIM;
    float sT1[8];
#pragma unroll
    for (int k = 0; k < 8; ++k) sT1[k] = T[k];
    const float T1a  = T[ia];
    const float T1b  = T[ib];
    const float T2ab = T[8 + lane];
    float T2b[8], T3v[8];
#pragma unroll
    for (int k = 0; k < 8; ++k) T2b[k] = T[8 + ib * 8 + k];
#pragma unroll
    for (int k = 0; k < 8; ++k) T3v[k] = T[72 + lane * 8 + k];
    const float R1o = R1a, R2o = R2;
#pragma unroll
    for (int k = 0; k < 8; ++k)
      R3[k] += T3v[k] + R1o * T2b[k] + R2o * sT1[k];
    R2  += T2ab + R1o * T1b;
    R1a += T1a;
  }

  float* o = out + (size_t)samp * SIGDIM;
  if (ib == 0) o[ia] = R1a;
  o[8 + lane] = R2;
#pragma unroll
  for (int k = 0; k < 8; ++k) o[72 + lane * 8 + k] = R3[k];
}

extern "C" void kernel_launch(void* const* d_in, const int* in_sizes, int n_in,
                              void* d_out, int out_size, void* d_ws, size_t ws_size,
                              hipStream_t stream) {
  (void)in_sizes; (void)n_in; (void)out_size;
  const float* path = (const float*)d_in[0];
  float* out = (float*)d_out;
  float* ws  = (float*)d_ws;

  int G = 16;
  while (G > 1 && (size_t)B_ * G * SIGDIM * sizeof(float) > ws_size) G >>= 1;
  const int CPC = (NINC + G - 1) / G;   // increments per chunk

  sig_chunks_kernel<<<dim3(B_ * G / 4), dim3(256), 0, stream>>>(path, ws, G, CPC);
  sig_combine_kernel<<<dim3(B_ / 4), dim3(256), 0, stream>>>(ws, out, G);
}

// Round 11
// 129.045 us; speedup vs baseline: 1.1476x; 1.1476x over previous
//
#include <hip/hip_runtime.h>

// Truncated signature, depth=3, C=8, B=512, L=8192.
// Kernel 1 (R4 structure + packed-fp32 VALU diet): one wave per (sample,chunk),
//   sequential Chen steps. lane (a,b)=(lane>>3,lane&7) owns S2[a][b], S3[a][b][*].
//   Direct form: S3[k] += cf * dx2[k][u];  cf = S2 + S1*db/2 + da*db/6.
//   dx/2 staged in BOTH LDS layouts (per-wave private, NO barriers):
//     Bc [c][t] stride 68          -> per-lane da/db b128 reads
//     A  [t][c] split 4+4 columns  -> uniform b128 broadcast reads (+AHOFF half)
//   VALU per step: 1 pk_fma (w,z pair) + 2 fma (cf,S2) + 1 fma (s1a)
//                  + 4 pk_fma (S3 as f2 k-pairs)  ~= 8 instructions.
// Kernel 2: per-sample in-order Chen combine of the G chunk signatures.

typedef float f2 __attribute__((ext_vector_type(2)));

constexpr int B_ = 512;
constexpr int C_ = 8;
constexpr int L_ = 8192;
constexpr int NINC = L_ - 1;      // 8191 increments
constexpr int SIGDIM = 584;       // 8 + 64 + 512
constexpr int TILE = 64;          // steps per LDS tile
constexpr int BSTR = 68;          // Bc row stride (floats)
constexpr int AHOFF = 264;        // A high-half offset (floats), bank +8, 16B-aligned
constexpr int AWSZ = 520;
constexpr int BWSZ = C_ * BSTR;   // 544

// One step. DAV/DBV are halved increments; PLO/PHI are dx/2 for channels 0-3/4-7.
#define SIG_STEP(DAV, DBV, PLO, PHI)                                       \
  do {                                                                     \
    const f2 wz = __builtin_elementwise_fma(                               \
        f2{(DAV), (DAV)}, f2{(2.f/3.f), (4.f/3.f)}, f2{s1a, s1a});         \
    const float cf = __builtin_fmaf((DBV), wz.x, S2);                      \
    S2  = __builtin_fmaf((DBV), wz.y, cf);                                 \
    s1a = __builtin_fmaf((DAV), 2.f, s1a);                                 \
    const f2 cf2 = {cf, cf};                                               \
    S3p[0] = __builtin_elementwise_fma(cf2, f2{(PLO).x, (PLO).y}, S3p[0]); \
    S3p[1] = __builtin_elementwise_fma(cf2, f2{(PLO).z, (PLO).w}, S3p[1]); \
    S3p[2] = __builtin_elementwise_fma(cf2, f2{(PHI).x, (PHI).y}, S3p[2]); \
    S3p[3] = __builtin_elementwise_fma(cf2, f2{(PHI).z, (PHI).w}, S3p[3]); \
  } while (0)

__global__ __launch_bounds__(256, 8)
void sig_chunks_kernel(const float* __restrict__ path, float* __restrict__ csig,
                       int G, int CPC) {
  __shared__ __align__(16) float As[4][AWSZ];
  __shared__ __align__(16) float Bs[4][BWSZ];
  const int wid  = __builtin_amdgcn_readfirstlane((int)(threadIdx.x >> 6));
  const int lane = (int)(threadIdx.x & 63);
  const int ia = lane >> 3;   // 'a' == staging channel
  const int ib = lane & 7;    // 'b' == staging position
  const int wglob = __builtin_amdgcn_readfirstlane((int)blockIdx.x) * 4 + wid;
  const int samp = wglob / G;
  const int g    = wglob - samp * G;
  const int ts = g * CPC;
  const int te = (ts + CPC < NINC) ? (ts + CPC) : NINC;   // exclusive end
  const float* pbase = path + (size_t)samp * (C_ * L_);
  float* as_ = As[wid];
  float* bs  = Bs[wid];

  const int si = ib;
  const float* prow = pbase + ia * L_;
  const int grp = lane & ~7;
  float* aw = as_ + (ia >> 2) * AHOFF + (ia & 3);

  f2 S3p[4];
#pragma unroll
  for (int k = 0; k < 4; ++k) S3p[k] = f2{0.f, 0.f};
  float S2 = 0.f, s1a = 0.f;

  const int ntiles = (CPC + TILE - 1) / TILE;   // uniform across grid

  // prologue: prefetch tile 0 + boundary
  float4 r0 = *(const float4*)(prow + ts + si * 4);
  float4 r1 = *(const float4*)(prow + ts + 32 + si * 4);
  float bnd = prow[ts + TILE];

  for (int tt = 0; tt < ntiles; ++tt) {
    const int t0 = ts + tt * TILE;
    const int cnt_ = te - t0;
    const int cnt = (cnt_ < TILE) ? cnt_ : TILE;

    // ---- stage tile tt from regs: halved diffs into both LDS layouts ----
    {
      const float4 v0 = r0, v1 = r1;
      const float sA = __shfl(v0.x, lane + 1);
      const float sB = __shfl(v1.x, grp);
      const float sC = __shfl(v1.x, lane + 1);
      const float n0 = (si == 7) ? sB : sA;
      const float n1 = (si == 7) ? bnd : sC;
      float4 d0, d1;
      d0.x = (v0.y - v0.x) * 0.5f;
      d0.y = (v0.z - v0.y) * 0.5f;
      d0.z = (v0.w - v0.z) * 0.5f;
      d0.w = (n0 - v0.w) * 0.5f;
      d1.x = (v1.y - v1.x) * 0.5f;
      d1.y = (v1.z - v1.y) * 0.5f;
      d1.z = (v1.w - v1.z) * 0.5f;
      d1.w = (n1 - v1.w) * 0.5f;
      *(float4*)(bs + ia * BSTR + si * 4) = d0;
      *(float4*)(bs + ia * BSTR + 32 + si * 4) = d1;
      const int tl = si * 4;
      aw[(tl + 0) * 4] = d0.x;
      aw[(tl + 1) * 4] = d0.y;
      aw[(tl + 2) * 4] = d0.z;
      aw[(tl + 3) * 4] = d0.w;
      aw[(32 + tl + 0) * 4] = d1.x;
      aw[(32 + tl + 1) * 4] = d1.y;
      aw[(32 + tl + 2) * 4] = d1.z;
      aw[(32 + tl + 3) * 4] = d1.w;
    }

    // ---- prefetch tile tt+1 ----
    if (tt + 1 < ntiles) {
      const int t1g = t0 + TILE;
      r0 = *(const float4*)(prow + t1g + si * 4);
      r1 = *(const float4*)(prow + t1g + 32 + si * 4);
      const int bn = t1g + TILE;
      bnd = (bn < L_) ? prow[bn] : 0.f;
    }

    // ---- compute tile tt ----
    if (cnt == TILE) {
#pragma unroll
      for (int blk = 0; blk < 8; ++blk) {
        const int u0 = blk * 8;
        const float4 a0 = *(const float4*)(bs + ia * BSTR + u0);
        const float4 a1 = *(const float4*)(bs + ia * BSTR + u0 + 4);
        const float4 b0 = *(const float4*)(bs + ib * BSTR + u0);
        const float4 b1 = *(const float4*)(bs + ib * BSTR + u0 + 4);
        // one-step-ahead rotation for the uniform row reads
        float4 P0 = *(const float4*)(as_ + u0 * 4);
        float4 P1 = *(const float4*)(as_ + AHOFF + u0 * 4);
        float4 Q0, Q1;
        Q0 = *(const float4*)(as_ + (u0 + 1) * 4);
        Q1 = *(const float4*)(as_ + AHOFF + (u0 + 1) * 4);
        SIG_STEP(a0.x, b0.x, P0, P1); P0 = Q0; P1 = Q1;
        Q0 = *(const float4*)(as_ + (u0 + 2) * 4);
        Q1 = *(const float4*)(as_ + AHOFF + (u0 + 2) * 4);
        SIG_STEP(a0.y, b0.y, P0, P1); P0 = Q0; P1 = Q1;
        Q0 = *(const float4*)(as_ + (u0 + 3) * 4);
        Q1 = *(const float4*)(as_ + AHOFF + (u0 + 3) * 4);
        SIG_STEP(a0.z, b0.z, P0, P1); P0 = Q0; P1 = Q1;
        Q0 = *(const float4*)(as_ + (u0 + 4) * 4);
        Q1 = *(const float4*)(as_ + AHOFF + (u0 + 4) * 4);
        SIG_STEP(a0.w, b0.w, P0, P1); P0 = Q0; P1 = Q1;
        Q0 = *(const float4*)(as_ + (u0 + 5) * 4);
        Q1 = *(const float4*)(as_ + AHOFF + (u0 + 5) * 4);
        SIG_STEP(a1.x, b1.x, P0, P1); P0 = Q0; P1 = Q1;
        Q0 = *(const float4*)(as_ + (u0 + 6) * 4);
        Q1 = *(const float4*)(as_ + AHOFF + (u0 + 6) * 4);
        SIG_STEP(a1.y, b1.y, P0, P1); P0 = Q0; P1 = Q1;
        Q0 = *(const float4*)(as_ + (u0 + 7) * 4);
        Q1 = *(const float4*)(as_ + AHOFF + (u0 + 7) * 4);
        SIG_STEP(a1.z, b1.z, P0, P1); P0 = Q0; P1 = Q1;
        SIG_STEP(a1.w, b1.w, P0, P1);
      }
    } else {
      // tail tile (only the last chunk's last tile, cnt=63): cold path
      for (int blk = 0; blk < 8; ++blk) {
        const int u0 = blk * 8;
        int m = cnt - u0; if (m > 8) m = 8;
        if (m <= 0) break;
        const float4 a0 = *(const float4*)(bs + ia * BSTR + u0);
        const float4 a1 = *(const float4*)(bs + ia * BSTR + u0 + 4);
        const float4 b0 = *(const float4*)(bs + ib * BSTR + u0);
        const float4 b1 = *(const float4*)(bs + ib * BSTR + u0 + 4);
        const float da[8] = {a0.x, a0.y, a0.z, a0.w, a1.x, a1.y, a1.z, a1.w};
        const float db[8] = {b0.x, b0.y, b0.z, b0.w, b1.x, b1.y, b1.z, b1.w};
#pragma unroll
        for (int u = 0; u < 8; ++u) {
          if (u < m) {
            const float4 PLO = *(const float4*)(as_ + (u0 + u) * 4);
            const float4 PHI = *(const float4*)(as_ + AHOFF + (u0 + u) * 4);
            SIG_STEP(da[u], db[u], PLO, PHI);
          }
        }
      }
    }
  }

  float* cs = csig + ((size_t)samp * G + g) * SIGDIM;
  if (ib == 0) cs[ia] = s1a;
  cs[8 + lane] = S2;
  float4 o0, o1;
  o0.x = 2.f * S3p[0].x; o0.y = 2.f * S3p[0].y;
  o0.z = 2.f * S3p[1].x; o0.w = 2.f * S3p[1].y;
  o1.x = 2.f * S3p[2].x; o1.y = 2.f * S3p[2].y;
  o1.z = 2.f * S3p[3].x; o1.w = 2.f * S3p[3].y;
  *(float4*)(cs + 72 + lane * 8)     = o0;
  *(float4*)(cs + 72 + lane * 8 + 4) = o1;
}

__global__ __launch_bounds__(256)
void sig_combine_kernel(const float* __restrict__ csig, float* __restrict__ out, int G) {
  const int wid  = __builtin_amdgcn_readfirstlane((int)(threadIdx.x >> 6));
  const int lane = (int)(threadIdx.x & 63);
  const int ia = lane >> 3, ib = lane & 7;
  const int samp = __builtin_amdgcn_readfirstlane((int)blockIdx.x) * 4 + wid;
  const float* base = csig + (size_t)samp * G * SIGDIM;

  float R1a = base[ia];
  float R2  = base[8 + lane];
  float R3[8];
#pragma unroll
  for (int k = 0; k < 8; ++k) R3[k] = base[72 + lane * 8 + k];

  for (int g = 1; g < G; ++g) {
    const float* T = base + g * SIGDIM;
    float sT1[8];
#pragma unroll
    for (int k = 0; k < 8; ++k) sT1[k] = T[k];
    const float T1a  = T[ia];
    const float T1b  = T[ib];
    const float T2ab = T[8 + lane];
    float T2b[8], T3v[8];
#pragma unroll
    for (int k = 0; k < 8; ++k) T2b[k] = T[8 + ib * 8 + k];
#pragma unroll
    for (int k = 0; k < 8; ++k) T3v[k] = T[72 + lane * 8 + k];
    const float R1o = R1a, R2o = R2;
#pragma unroll
    for (int k = 0; k < 8; ++k)
      R3[k] += T3v[k] + R1o * T2b[k] + R2o * sT1[k];
    R2  += T2ab + R1o * T1b;
    R1a += T1a;
  }

  float* o = out + (size_t)samp * SIGDIM;
  if (ib == 0) o[ia] = R1a;
  o[8 + lane] = R2;
#pragma unroll
  for (int k = 0; k < 8; ++k) o[72 + lane * 8 + k] = R3[k];
}

extern "C" void kernel_launch(void* const* d_in, const int* in_sizes, int n_in,
                              void* d_out, int out_size, void* d_ws, size_t ws_size,
                              hipStream_t stream) {
  (void)in_sizes; (void)n_in; (void)out_size;
  const float* path = (const float*)d_in[0];
  float* out = (float*)d_out;
  float* ws  = (float*)d_ws;

  int G = 16;
  while (G > 1 && (size_t)B_ * G * SIGDIM * sizeof(float) > ws_size) G >>= 1;
  const int CPC = (NINC + G - 1) / G;   // increments per chunk

  sig_chunks_kernel<<<dim3(B_ * G / 4), dim3(256), 0, stream>>>(path, ws, G, CPC);
  sig_combine_kernel<<<dim3(B_ / 4), dim3(256), 0, stream>>>(ws, out, G);
}